// Round 1
// baseline (1002.930 us; speedup 1.0000x reference)
//
#include <hip/hip_runtime.h>
#include <hip/hip_bf16.h>
#include <math.h>

// Problem constants
#define BATCH 8
#define CIN   384
#define NPIX  1024           // 32*32
#define OQKV  1536
#define NHEAD 8
#define DK    32
#define DV    128

__device__ __forceinline__ float gelu_exact(float v) {
    return 0.5f * v * (1.0f + erff(v * 0.70710678118654752f));
}

// ---------------------------------------------------------------------------
// GEMM: Out[b,o,n] = sum_c W[o,c] * X[b,c,n]
// 128x128 tile, K-tile 16, 8x8 per thread, 256 threads.
// ---------------------------------------------------------------------------
__global__ __launch_bounds__(256) void gemm_conv1x1(
    const float* __restrict__ X,   // (B, Cin, 1024)
    const float* __restrict__ W,   // (O, Cin)
    float* __restrict__ Out,       // (B, O, 1024)
    int O, int Cin)
{
    __shared__ float w_s[16][132];  // [kk][o]
    __shared__ float x_s[16][132];  // [kk][n]

    const int b  = blockIdx.z;
    const int o0 = blockIdx.y * 128;
    const int n0 = blockIdx.x * 128;
    const int tid = threadIdx.x;
    const int ty = tid >> 4;    // 0..15  (o-groups of 8)
    const int tx = tid & 15;    // 0..15  (n-groups of 8)

    float acc[8][8] = {};

    const float* Xb = X + (size_t)b * Cin * NPIX + n0;

    for (int k0 = 0; k0 < Cin; k0 += 16) {
        // W tile: 128 rows x 16 cols  (store transposed)
        #pragma unroll
        for (int r = 0; r < 2; ++r) {
            int idx = tid + r * 256;          // 0..511 float4 idx
            int row = idx >> 2;               // 0..127
            int c4  = idx & 3;                // 0..3
            float4 w4 = *(const float4*)&W[(size_t)(o0 + row) * Cin + k0 + c4 * 4];
            w_s[c4 * 4 + 0][row] = w4.x;
            w_s[c4 * 4 + 1][row] = w4.y;
            w_s[c4 * 4 + 2][row] = w4.z;
            w_s[c4 * 4 + 3][row] = w4.w;
        }
        // X tile: 16 rows(c) x 128 cols(n)
        #pragma unroll
        for (int r = 0; r < 2; ++r) {
            int idx = tid + r * 256;
            int row = idx >> 5;               // 0..15
            int n4  = idx & 31;               // 0..31
            float4 xv = *(const float4*)&Xb[(size_t)(k0 + row) * NPIX + n4 * 4];
            *(float4*)&x_s[row][n4 * 4] = xv;
        }
        __syncthreads();

        #pragma unroll
        for (int kk = 0; kk < 16; ++kk) {
            float a[8], bb[8];
            *(float4*)&a[0]  = *(const float4*)&w_s[kk][ty * 8];
            *(float4*)&a[4]  = *(const float4*)&w_s[kk][ty * 8 + 4];
            *(float4*)&bb[0] = *(const float4*)&x_s[kk][tx * 8];
            *(float4*)&bb[4] = *(const float4*)&x_s[kk][tx * 8 + 4];
            #pragma unroll
            for (int i = 0; i < 8; ++i)
                #pragma unroll
                for (int j = 0; j < 8; ++j)
                    acc[i][j] += a[i] * bb[j];
        }
        __syncthreads();
    }

    float* Ob = Out + ((size_t)b * O + o0) * NPIX + n0;
    #pragma unroll
    for (int i = 0; i < 8; ++i) {
        int o = ty * 8 + i;
        *(float4*)&Ob[(size_t)o * NPIX + tx * 8]     =
            make_float4(acc[i][0], acc[i][1], acc[i][2], acc[i][3]);
        *(float4*)&Ob[(size_t)o * NPIX + tx * 8 + 4] =
            make_float4(acc[i][4], acc[i][5], acc[i][6], acc[i][7]);
    }
}

// ---------------------------------------------------------------------------
// BN stats: per-channel mean/var over (B, N) -> scale/shift
// One block per channel, 256 threads, 8192 values.
// ---------------------------------------------------------------------------
__global__ __launch_bounds__(256) void bn_stats(
    const float* __restrict__ Y,      // (B, O, 1024)
    const float* __restrict__ gamma,
    const float* __restrict__ beta,
    float* __restrict__ stats,        // (O, 2): scale, shift
    int O)
{
    const int ch = blockIdx.x;
    const int tid = threadIdx.x;
    const float* base = Y + (size_t)ch * NPIX;

    float s = 0.f, ss = 0.f;
    #pragma unroll
    for (int b = 0; b < BATCH; ++b) {
        float4 v = *(const float4*)&base[(size_t)b * O * NPIX + tid * 4];
        s  += v.x + v.y + v.z + v.w;
        ss += v.x * v.x + v.y * v.y + v.z * v.z + v.w * v.w;
    }
    #pragma unroll
    for (int m = 1; m < 64; m <<= 1) {
        s  += __shfl_xor(s, m);
        ss += __shfl_xor(ss, m);
    }
    __shared__ float rs[4], rss[4];
    if ((tid & 63) == 0) { rs[tid >> 6] = s; rss[tid >> 6] = ss; }
    __syncthreads();
    if (tid == 0) {
        float S  = rs[0] + rs[1] + rs[2] + rs[3];
        float SS = rss[0] + rss[1] + rss[2] + rss[3];
        float mean = S * (1.0f / 8192.0f);
        float var  = SS * (1.0f / 8192.0f) - mean * mean;
        float sc = gamma[ch] / sqrtf(var + 1e-5f);
        stats[ch * 2 + 0] = sc;
        stats[ch * 2 + 1] = beta[ch] - mean * sc;
    }
}

// ---------------------------------------------------------------------------
// Fused attention: reads raw qkv + BN stats, applies BN on load,
// flash-style online softmax, writes gelu(attn_out) as (B, 1024, 1024).
// One block per (b, h, 128-query block). 256 threads.
// ---------------------------------------------------------------------------
__global__ __launch_bounds__(256) void attn_kernel(
    const float* __restrict__ QKV,    // (B, 1536, 1024) raw conv output
    const float* __restrict__ st,     // stats (1536, 2)
    float* __restrict__ Og)           // (B, 1024, 1024)
{
    __shared__ float q_s[32][136];    // [d][q] 128 queries
    __shared__ float k_s[32][68];     // [d][m] 64 keys
    __shared__ float v_t[64][132];    // [m][d] 128 dv
    __shared__ float s_t[64][132];    // [m][q] P transposed

    const int b  = blockIdx.z;
    const int h  = blockIdx.y;
    const int q0 = blockIdx.x * 128;
    const int tid = threadIdx.x;
    const int tq = tid >> 4;     // 0..15 : q rows tq*8 .. tq*8+7
    const int tm = tid & 15;     // S phase: m group; PV phase: d group
    const float invsq = 0.17677669529663687f;  // 1/sqrt(32)

    const size_t base = ((size_t)b * OQKV + h * 192) * NPIX;
    const int chb = h * 192;

    // stage Q (normalized, pre-scaled)
    #pragma unroll
    for (int r = 0; r < 4; ++r) {
        int fidx = tid + r * 256;     // 0..1023
        int d  = fidx >> 5;           // 0..31
        int q4 = fidx & 31;
        float sc = st[(chb + d) * 2], sh = st[(chb + d) * 2 + 1];
        float4 v = *(const float4*)&QKV[base + (size_t)d * NPIX + q0 + q4 * 4];
        v.x = (v.x * sc + sh) * invsq;
        v.y = (v.y * sc + sh) * invsq;
        v.z = (v.z * sc + sh) * invsq;
        v.w = (v.w * sc + sh) * invsq;
        *(float4*)&q_s[d][q4 * 4] = v;
    }

    float acc[8][8] = {};
    float m_run[8], l_run[8];
    #pragma unroll
    for (int i = 0; i < 8; ++i) { m_run[i] = -INFINITY; l_run[i] = 0.f; }

    for (int mt = 0; mt < 16; ++mt) {
        const int m0 = mt * 64;
        // stage K (normalized): 32 x 64
        #pragma unroll
        for (int r = 0; r < 2; ++r) {
            int fidx = tid + r * 256;   // 0..511
            int d  = fidx >> 4;         // 0..31
            int m4 = fidx & 15;
            float sc = st[(chb + 32 + d) * 2], sh = st[(chb + 32 + d) * 2 + 1];
            float4 v = *(const float4*)&QKV[base + (size_t)(32 + d) * NPIX + m0 + m4 * 4];
            v.x = v.x * sc + sh; v.y = v.y * sc + sh;
            v.z = v.z * sc + sh; v.w = v.w * sc + sh;
            *(float4*)&k_s[d][m4 * 4] = v;
        }
        // stage V transposed (normalized): 128 x 64 -> v_t[m][d]
        #pragma unroll
        for (int r = 0; r < 8; ++r) {
            int fidx = tid + r * 256;   // 0..2047
            int d  = fidx >> 4;         // 0..127
            int m4 = fidx & 15;
            float sc = st[(chb + 64 + d) * 2], sh = st[(chb + 64 + d) * 2 + 1];
            float4 v = *(const float4*)&QKV[base + (size_t)(64 + d) * NPIX + m0 + m4 * 4];
            v_t[m4 * 4 + 0][d] = v.x * sc + sh;
            v_t[m4 * 4 + 1][d] = v.y * sc + sh;
            v_t[m4 * 4 + 2][d] = v.z * sc + sh;
            v_t[m4 * 4 + 3][d] = v.w * sc + sh;
        }
        __syncthreads();

        // S = Q^T K : each thread 8q x 4m
        float s[8][4] = {};
        #pragma unroll
        for (int d = 0; d < 32; ++d) {
            float qq[8], kk4[4];
            *(float4*)&qq[0]  = *(const float4*)&q_s[d][tq * 8];
            *(float4*)&qq[4]  = *(const float4*)&q_s[d][tq * 8 + 4];
            *(float4*)&kk4[0] = *(const float4*)&k_s[d][tm * 4];
            #pragma unroll
            for (int i = 0; i < 8; ++i)
                #pragma unroll
                for (int j = 0; j < 4; ++j)
                    s[i][j] += qq[i] * kk4[j];
        }

        // online softmax per q row (16-lane groups share a row set)
        #pragma unroll
        for (int i = 0; i < 8; ++i) {
            float rmax = fmaxf(fmaxf(s[i][0], s[i][1]), fmaxf(s[i][2], s[i][3]));
            #pragma unroll
            for (int msk = 1; msk < 16; msk <<= 1)
                rmax = fmaxf(rmax, __shfl_xor(rmax, msk));
            float mnew = fmaxf(m_run[i], rmax);
            float f = __expf(m_run[i] - mnew);
            float p[4], rsum = 0.f;
            #pragma unroll
            for (int j = 0; j < 4; ++j) { p[j] = __expf(s[i][j] - mnew); rsum += p[j]; }
            #pragma unroll
            for (int msk = 1; msk < 16; msk <<= 1)
                rsum += __shfl_xor(rsum, msk);
            l_run[i] = l_run[i] * f + rsum;
            m_run[i] = mnew;
            #pragma unroll
            for (int j = 0; j < 8; ++j) acc[i][j] *= f;
            #pragma unroll
            for (int j = 0; j < 4; ++j) s_t[tm * 4 + j][tq * 8 + i] = p[j];
        }
        __syncthreads();

        // PV: O[8q][8d] += P[8q][mm] * V[mm][8d]; d split in two halves
        #pragma unroll 4
        for (int mm = 0; mm < 64; ++mm) {
            float pp[8], vv[8];
            *(float4*)&pp[0] = *(const float4*)&s_t[mm][tq * 8];
            *(float4*)&pp[4] = *(const float4*)&s_t[mm][tq * 8 + 4];
            *(float4*)&vv[0] = *(const float4*)&v_t[mm][tm * 4];
            *(float4*)&vv[4] = *(const float4*)&v_t[mm][64 + tm * 4];
            #pragma unroll
            for (int i = 0; i < 8; ++i)
                #pragma unroll
                for (int j = 0; j < 8; ++j)
                    acc[i][j] += pp[i] * vv[j];
        }
        __syncthreads();
    }

    // epilogue: normalize, gelu, store (B, H*128, N) layout
    const size_t obase = ((size_t)b * 1024 + h * DV) * NPIX + q0;
    #pragma unroll
    for (int i = 0; i < 8; ++i) {
        float inv = 1.0f / l_run[i];
        int q = tq * 8 + i;
        #pragma unroll
        for (int j = 0; j < 8; ++j) {
            int d = (j < 4) ? (tm * 4 + j) : (64 + tm * 4 + (j - 4));
            float o = acc[i][j] * inv;
            Og[obase + (size_t)d * NPIX + q] = gelu_exact(o);
        }
    }
}

// ---------------------------------------------------------------------------
// Fused BN-apply (+ optional residual, optional gelu), elementwise float4.
// ---------------------------------------------------------------------------
__global__ __launch_bounds__(256) void bn_apply(
    const float* __restrict__ raw,    // (B, O, 1024)
    const float* __restrict__ st,     // (O, 2)
    const float* __restrict__ resid,  // nullable
    float* __restrict__ out,
    int O, int do_gelu)
{
    size_t i4 = (size_t)blockIdx.x * 256 + threadIdx.x;
    size_t total4 = (size_t)BATCH * O * (NPIX / 4);
    if (i4 >= total4) return;
    size_t i = i4 * 4;
    int ch = (int)((i >> 10) % O);
    float sc = st[ch * 2], sh = st[ch * 2 + 1];
    float4 r = *(const float4*)&raw[i];
    float4 o;
    o.x = r.x * sc + sh; o.y = r.y * sc + sh;
    o.z = r.z * sc + sh; o.w = r.w * sc + sh;
    if (do_gelu) {
        o.x = gelu_exact(o.x); o.y = gelu_exact(o.y);
        o.z = gelu_exact(o.z); o.w = gelu_exact(o.w);
    }
    if (resid) {
        float4 rr = *(const float4*)&resid[i];
        o.x += rr.x; o.y += rr.y; o.z += rr.z; o.w += rr.w;
    }
    *(float4*)&out[i] = o;
}

// ---------------------------------------------------------------------------
extern "C" void kernel_launch(void* const* d_in, const int* in_sizes, int n_in,
                              void* d_out, int out_size, void* d_ws, size_t ws_size,
                              hipStream_t stream)
{
    const float* x       = (const float*)d_in[0];
    const float* w_qkv   = (const float*)d_in[1];
    const float* g_qkv   = (const float*)d_in[2];
    const float* b_qkv   = (const float*)d_in[3];
    const float* w_merge = (const float*)d_in[4];
    const float* g_merge = (const float*)d_in[5];
    const float* b_merge = (const float*)d_in[6];
    const float* w_fc1   = (const float*)d_in[7];
    const float* g_fc1   = (const float*)d_in[8];
    const float* b_fc1   = (const float*)d_in[9];
    const float* w_fc2   = (const float*)d_in[10];
    const float* g_fc2   = (const float*)d_in[11];
    const float* b_fc2   = (const float*)d_in[12];
    float* out = (float*)d_out;

    float* ws = (float*)d_ws;
    float* qkv_raw  = ws;                  // 12,582,912 floats
    float* attn_out = ws + 12582912;       //  8,388,608
    float* merge_raw = ws;                 //  3,145,728 (reuse: qkv dead)
    float* x2       = ws + 3145728;        //  3,145,728
    float* fc1_raw  = ws + 6291456;        //  6,291,456
    float* h_act    = ws + 12582912;       //  6,291,456 (reuse: attn dead)
    float* fc2_raw  = ws;                  //  3,145,728 (reuse: merge dead)
    float* st1 = ws + 20971520;            // 1536*2
    float* st2 = st1 + 3072;               // 384*2
    float* st3 = st2 + 768;                // 768*2
    float* st4 = st3 + 1536;               // 384*2

    // 1. qkv = conv1x1(x, w_qkv)
    gemm_conv1x1<<<dim3(8, 12, 8), 256, 0, stream>>>(x, w_qkv, qkv_raw, OQKV, CIN);
    // 2. BN stats for qkv
    bn_stats<<<dim3(OQKV), 256, 0, stream>>>(qkv_raw, g_qkv, b_qkv, st1, OQKV);
    // 3. fused attention (+BN apply on load, gelu on store)
    attn_kernel<<<dim3(8, 8, 8), 256, 0, stream>>>(qkv_raw, st1, attn_out);
    // 4. merge conv
    gemm_conv1x1<<<dim3(8, 3, 8), 256, 0, stream>>>(attn_out, w_merge, merge_raw, 384, 1024);
    // 5. BN stats merge
    bn_stats<<<dim3(384), 256, 0, stream>>>(merge_raw, g_merge, b_merge, st2, 384);
    // 6. x2 = x + bn(merge)
    bn_apply<<<dim3(3072), 256, 0, stream>>>(merge_raw, st2, x, x2, 384, 0);
    // 7. fc1
    gemm_conv1x1<<<dim3(8, 6, 8), 256, 0, stream>>>(x2, w_fc1, fc1_raw, 768, CIN);
    // 8. BN stats fc1
    bn_stats<<<dim3(768), 256, 0, stream>>>(fc1_raw, g_fc1, b_fc1, st3, 768);
    // 9. h = gelu(bn(fc1))
    bn_apply<<<dim3(6144), 256, 0, stream>>>(fc1_raw, st3, nullptr, h_act, 768, 1);
    // 10. fc2
    gemm_conv1x1<<<dim3(8, 3, 8), 256, 0, stream>>>(h_act, w_fc2, fc2_raw, 384, 768);
    // 11. BN stats fc2
    bn_stats<<<dim3(384), 256, 0, stream>>>(fc2_raw, g_fc2, b_fc2, st4, 384);
    // 12. out = x2 + bn(fc2)
    bn_apply<<<dim3(3072), 256, 0, stream>>>(fc2_raw, st4, x2, out, 384, 0);
}

// Round 2
// 356.051 us; speedup vs baseline: 2.8168x; 2.8168x over previous
//
#include <hip/hip_runtime.h>
#include <hip/hip_bf16.h>
#include <math.h>

// ---------------------------------------------------------------------------
// Layout strategy (bf16 MFMA rewrite):
//   All activations live as row-major [8192 rows = b*1024+pixel][channels],
//   channels contiguous -> every GEMM is D[row][o] = sum_c A[row][c]*W[o][c],
//   both operands k-contiguous => 16B LDS staging + ds_read_b128 fragments.
//   BN stats fused into GEMM epilogue via per-column atomicAdd(s, ss).
//   mfma_f32_16x16x32_bf16: A row = lane&15, k = (lane>>4)*8+j (consistent
//   convention both operands => k-permutation-invariant correct).
//   C/D layout (verified m89): col = lane&15, row = (lane>>4)*4 + reg.
// ---------------------------------------------------------------------------

#define ROWS 8192          // b * 1024 pixels
#define NPIX 1024

typedef __attribute__((ext_vector_type(8))) short short8;
typedef __attribute__((ext_vector_type(4))) float f32x4;

__device__ __forceinline__ float gelu_exact(float v) {
    return 0.5f * v * (1.0f + erff(v * 0.70710678118654752f));
}
__device__ __forceinline__ short f2bf(float f) {   // RNE float->bf16
    unsigned u = __float_as_uint(f);
    unsigned r = (u + 0x7fffu + ((u >> 16) & 1u)) >> 16;
    return (short)r;
}
__device__ __forceinline__ unsigned long long pack4bf(float a, float b, float c, float d) {
    return  (unsigned long long)(unsigned short)f2bf(a)
         | ((unsigned long long)(unsigned short)f2bf(b) << 16)
         | ((unsigned long long)(unsigned short)f2bf(c) << 32)
         | ((unsigned long long)(unsigned short)f2bf(d) << 48);
}

// ---------------------------------------------------------------------------
// cast fp32 -> bf16 (weights), 8 elements/thread
// ---------------------------------------------------------------------------
__global__ __launch_bounds__(256) void cast_bf(const float* __restrict__ s,
                                               short* __restrict__ d, int n8) {
    int t = blockIdx.x * 256 + threadIdx.x;
    if (t >= n8) return;
    float4 a = *(const float4*)&s[(size_t)t * 8];
    float4 b = *(const float4*)&s[(size_t)t * 8 + 4];
    short8 o;
    o[0]=f2bf(a.x); o[1]=f2bf(a.y); o[2]=f2bf(a.z); o[3]=f2bf(a.w);
    o[4]=f2bf(b.x); o[5]=f2bf(b.y); o[6]=f2bf(b.z); o[7]=f2bf(b.w);
    *(short8*)&d[(size_t)t * 8] = o;
}

// ---------------------------------------------------------------------------
// x (B,C,N) fp32 -> x_bf [row][384] bf16 + x_tf [row][384] fp32 (transpose)
// ---------------------------------------------------------------------------
__global__ __launch_bounds__(256) void x_transpose(
    const float* __restrict__ x, short* __restrict__ x_bf, float* __restrict__ x_tf)
{
    __shared__ float ls[64][65];
    const int b = blockIdx.z, c0 = blockIdx.y * 64, n0 = blockIdx.x * 64;
    const int rl = threadIdx.x >> 6, ll = threadIdx.x & 63;
    #pragma unroll
    for (int it = 0; it < 16; ++it) {
        int c = rl + it * 4;
        ls[c][ll] = x[((size_t)b * 384 + c0 + c) * NPIX + n0 + ll];
    }
    __syncthreads();
    #pragma unroll
    for (int it = 0; it < 16; ++it) {
        int n = rl + it * 4;
        float v = ls[ll][n];
        size_t row = (size_t)b * NPIX + n0 + n;
        x_tf[row * 384 + c0 + ll] = v;
        x_bf[row * 384 + c0 + ll] = f2bf(v);
    }
}

// ---------------------------------------------------------------------------
// GEMM bf16 MFMA: D[row][o] = sum_k A[row][k] * Wt[o][k], fp32 out.
// 128x128 tile, BK=64, 4 waves (2x2 of 64x64), fused BN-stat atomics.
// ---------------------------------------------------------------------------
#define LDK 72
__global__ __launch_bounds__(256) void gemm_bf16(
    const short* __restrict__ A, const short* __restrict__ Wt,
    float* __restrict__ D, float* __restrict__ sums, int O, int K)
{
    __shared__ short a_s[128 * LDK];
    __shared__ short w_s[128 * LDK];
    const int tid = threadIdx.x;
    const int wave = tid >> 6, lane = tid & 63;
    const int l16 = lane & 15, lhi = lane >> 4;
    const int m0 = blockIdx.x * 128, o0 = blockIdx.y * 128;
    const int wm = (wave & 1) * 64, wo = (wave >> 1) * 64;

    f32x4 acc[4][4];
    #pragma unroll
    for (int i = 0; i < 4; ++i)
        #pragma unroll
        for (int j = 0; j < 4; ++j) acc[i][j] = (f32x4){0.f, 0.f, 0.f, 0.f};

    for (int k0 = 0; k0 < K; k0 += 64) {
        #pragma unroll
        for (int it = 0; it < 4; ++it) {
            int idx = tid + it * 256;
            int r = idx >> 3, ch = idx & 7;
            *(float4*)&a_s[r * LDK + ch * 8] =
                *(const float4*)&A[(size_t)(m0 + r) * K + k0 + ch * 8];
            *(float4*)&w_s[r * LDK + ch * 8] =
                *(const float4*)&Wt[(size_t)(o0 + r) * K + k0 + ch * 8];
        }
        __syncthreads();
        #pragma unroll
        for (int kb = 0; kb < 2; ++kb) {
            short8 af[4], wf[4];
            #pragma unroll
            for (int i = 0; i < 4; ++i)
                af[i] = *(const short8*)&a_s[(wm + i * 16 + l16) * LDK + kb * 32 + lhi * 8];
            #pragma unroll
            for (int j = 0; j < 4; ++j)
                wf[j] = *(const short8*)&w_s[(wo + j * 16 + l16) * LDK + kb * 32 + lhi * 8];
            #pragma unroll
            for (int i = 0; i < 4; ++i)
                #pragma unroll
                for (int j = 0; j < 4; ++j)
                    acc[i][j] = __builtin_amdgcn_mfma_f32_16x16x32_bf16(af[i], wf[j], acc[i][j], 0, 0, 0);
        }
        __syncthreads();
    }

    // write D
    #pragma unroll
    for (int i = 0; i < 4; ++i) {
        #pragma unroll
        for (int r = 0; r < 4; ++r) {
            size_t row = (size_t)(m0 + wm + i * 16 + lhi * 4 + r);
            #pragma unroll
            for (int j = 0; j < 4; ++j)
                D[row * O + o0 + wo + j * 16 + l16] = acc[i][j][r];
        }
    }
    // fused BN partial stats
    #pragma unroll
    for (int j = 0; j < 4; ++j) {
        float s1 = 0.f, s2 = 0.f;
        #pragma unroll
        for (int i = 0; i < 4; ++i)
            #pragma unroll
            for (int r = 0; r < 4; ++r) { float v = acc[i][j][r]; s1 += v; s2 += v * v; }
        s1 += __shfl_xor(s1, 16); s1 += __shfl_xor(s1, 32);
        s2 += __shfl_xor(s2, 16); s2 += __shfl_xor(s2, 32);
        if (lhi == 0) {
            int col = o0 + wo + j * 16 + l16;
            atomicAdd(&sums[col * 2], s1);
            atomicAdd(&sums[col * 2 + 1], s2);
        }
    }
}

// ---------------------------------------------------------------------------
__global__ __launch_bounds__(256) void bn_finalize(
    const float* __restrict__ sums, const float* __restrict__ gamma,
    const float* __restrict__ beta, float* __restrict__ st, int O)
{
    int ch = blockIdx.x * 256 + threadIdx.x;
    if (ch >= O) return;
    float s = sums[ch * 2], ss = sums[ch * 2 + 1];
    float mean = s * (1.0f / 8192.0f);
    float var = ss * (1.0f / 8192.0f) - mean * mean;
    float sc = gamma[ch] * rsqrtf(var + 1e-5f);
    st[ch * 2] = sc;
    st[ch * 2 + 1] = beta[ch] - mean * sc;
}

// ---------------------------------------------------------------------------
// qkv raw [row][1536] -> normalized bf16 q,k channels [row][512]
// (q channels pre-scaled by 1/sqrt(32))
// ---------------------------------------------------------------------------
__global__ __launch_bounds__(256) void qkv_post(
    const float* __restrict__ raw, const float* __restrict__ st, short* __restrict__ qk)
{
    int t = blockIdx.x * 256 + threadIdx.x;       // ROWS*128
    int row = t >> 7, g = t & 127;
    int c = g * 4;
    int h = c >> 6, r = c & 63;
    int ch = h * 192 + r;
    float4 v = *(const float4*)&raw[(size_t)row * 1536 + ch];
    float4 sa = *(const float4*)&st[ch * 2];
    float4 sb = *(const float4*)&st[ch * 2 + 4];
    float o0 = v.x * sa.x + sa.y, o1 = v.y * sa.z + sa.w;
    float o2 = v.z * sb.x + sb.y, o3 = v.w * sb.z + sb.w;
    if (r < 32) {
        const float invsq = 0.17677669529663687f;
        o0 *= invsq; o1 *= invsq; o2 *= invsq; o3 *= invsq;
    }
    *(unsigned long long*)&qk[(size_t)row * 512 + c] = pack4bf(o0, o1, o2, o3);
}

// ---------------------------------------------------------------------------
// v channels: raw [row][1536] -> normalized bf16 V^T  vt[b*8+h][dv(128)][n(1024)]
// ---------------------------------------------------------------------------
__global__ __launch_bounds__(256) void v_transpose(
    const float* __restrict__ raw, const float* __restrict__ st, short* __restrict__ vt)
{
    __shared__ short ls[64][72];
    const int bh = blockIdx.z, b = bh >> 3, h = bh & 7;
    const int dv0 = blockIdx.y * 64, n0 = blockIdx.x * 64;
    const int rl = threadIdx.x >> 6, ll = threadIdx.x & 63;
    const int ch = h * 192 + 64 + dv0 + ll;
    const float sc = st[ch * 2], sh = st[ch * 2 + 1];
    #pragma unroll
    for (int it = 0; it < 16; ++it) {
        int n = rl + it * 4;
        float v = raw[((size_t)b * NPIX + n0 + n) * 1536 + ch] * sc + sh;
        ls[n][ll] = f2bf(v);
    }
    __syncthreads();
    #pragma unroll
    for (int it = 0; it < 16; ++it) {
        int dv = rl + it * 4;
        vt[((size_t)bh * 128 + dv0 + dv) * NPIX + n0 + ll] = ls[ll][dv];
    }
}

// ---------------------------------------------------------------------------
// Flash attention bf16 MFMA. Block: (qtile, h, b), 4 waves, wave = 32 q rows.
// Writes gelu(attn out) bf16 [row][1024].
// ---------------------------------------------------------------------------
__global__ __launch_bounds__(256) void attn_kernel(
    const short* __restrict__ qk, const short* __restrict__ vt, short* __restrict__ outp)
{
    __shared__ short k_s[64 * 40];
    __shared__ short vt_s[128 * 72];
    __shared__ short p_s[4 * 32 * 72];

    const int qt = blockIdx.x, h = blockIdx.y, b = blockIdx.z;
    const int q0 = qt * 128;
    const int tid = threadIdx.x;
    const int wave = tid >> 6, lane = tid & 63;
    const int l16 = lane & 15, lhi = lane >> 4;
    const int wq = wave * 32;
    short* pw = &p_s[wave * 32 * 72];

    short8 qf[2];
    #pragma unroll
    for (int fq = 0; fq < 2; ++fq) {
        size_t row = (size_t)b * NPIX + q0 + wq + fq * 16 + l16;
        qf[fq] = *(const short8*)&qk[row * 512 + h * 64 + lhi * 8];
    }

    f32x4 acc[2][8];
    #pragma unroll
    for (int i = 0; i < 2; ++i)
        #pragma unroll
        for (int j = 0; j < 8; ++j) acc[i][j] = (f32x4){0.f, 0.f, 0.f, 0.f};
    float m_run[2][4], l_run[2][4];
    #pragma unroll
    for (int i = 0; i < 2; ++i)
        #pragma unroll
        for (int r = 0; r < 4; ++r) { m_run[i][r] = -1e30f; l_run[i][r] = 0.f; }

    for (int mt = 0; mt < 16; ++mt) {
        const int m0 = mt * 64;
        {   // stage K tile: 64 m x 32 d
            int r = tid >> 2, ch = tid & 3;
            size_t row = (size_t)b * NPIX + m0 + r;
            *(float4*)&k_s[r * 40 + ch * 8] =
                *(const float4*)&qk[row * 512 + h * 64 + 32 + ch * 8];
        }
        #pragma unroll
        for (int it = 0; it < 4; ++it) {   // stage V^T tile: 128 dv x 64 m
            int idx = tid + it * 256;
            int r = idx >> 3, ch = idx & 7;
            *(float4*)&vt_s[r * 72 + ch * 8] =
                *(const float4*)&vt[((size_t)(b * 8 + h) * 128 + r) * NPIX + m0 + ch * 8];
        }
        __syncthreads();

        f32x4 s[2][4];
        #pragma unroll
        for (int i = 0; i < 2; ++i)
            #pragma unroll
            for (int j = 0; j < 4; ++j) s[i][j] = (f32x4){0.f, 0.f, 0.f, 0.f};
        #pragma unroll
        for (int fm = 0; fm < 4; ++fm) {
            short8 kf = *(const short8*)&k_s[(fm * 16 + l16) * 40 + lhi * 8];
            #pragma unroll
            for (int fq = 0; fq < 2; ++fq)
                s[fq][fm] = __builtin_amdgcn_mfma_f32_16x16x32_bf16(qf[fq], kf, s[fq][fm], 0, 0, 0);
        }

        // online softmax (rows owned per lane: q = fq*16 + lhi*4 + rr)
        #pragma unroll
        for (int fq = 0; fq < 2; ++fq) {
            #pragma unroll
            for (int rr = 0; rr < 4; ++rr) {
                float mx = fmaxf(fmaxf(s[fq][0][rr], s[fq][1][rr]),
                                 fmaxf(s[fq][2][rr], s[fq][3][rr]));
                #pragma unroll
                for (int msk = 1; msk < 16; msk <<= 1) mx = fmaxf(mx, __shfl_xor(mx, msk));
                float mo = m_run[fq][rr];
                float mn = fmaxf(mo, mx);
                float f = __expf(mo - mn);
                m_run[fq][rr] = mn;
                int qrow = fq * 16 + lhi * 4 + rr;
                float rsum = 0.f;
                #pragma unroll
                for (int fm = 0; fm < 4; ++fm) {
                    float p = __expf(s[fq][fm][rr] - mn);
                    rsum += p;
                    pw[qrow * 72 + fm * 16 + l16] = f2bf(p);
                }
                #pragma unroll
                for (int msk = 1; msk < 16; msk <<= 1) rsum += __shfl_xor(rsum, msk);
                l_run[fq][rr] = l_run[fq][rr] * f + rsum;
                #pragma unroll
                for (int fdv = 0; fdv < 8; ++fdv) acc[fq][fdv][rr] *= f;
            }
        }
        __syncthreads();

        // PV
        #pragma unroll
        for (int kc = 0; kc < 2; ++kc) {
            short8 pf[2];
            pf[0] = *(const short8*)&pw[(l16) * 72 + kc * 32 + lhi * 8];
            pf[1] = *(const short8*)&pw[(16 + l16) * 72 + kc * 32 + lhi * 8];
            #pragma unroll
            for (int fdv = 0; fdv < 8; ++fdv) {
                short8 vf = *(const short8*)&vt_s[(fdv * 16 + l16) * 72 + kc * 32 + lhi * 8];
                #pragma unroll
                for (int fq = 0; fq < 2; ++fq)
                    acc[fq][fdv] = __builtin_amdgcn_mfma_f32_16x16x32_bf16(pf[fq], vf, acc[fq][fdv], 0, 0, 0);
            }
        }
        __syncthreads();
    }

    #pragma unroll
    for (int fq = 0; fq < 2; ++fq) {
        #pragma unroll
        for (int rr = 0; rr < 4; ++rr) {
            float inv = 1.0f / l_run[fq][rr];
            size_t row = (size_t)b * NPIX + q0 + wq + fq * 16 + lhi * 4 + rr;
            #pragma unroll
            for (int fdv = 0; fdv < 8; ++fdv) {
                float o = acc[fq][fdv][rr] * inv;
                outp[row * 1024 + h * 128 + fdv * 16 + l16] = f2bf(gelu_exact(o));
            }
        }
    }
}

// ---------------------------------------------------------------------------
// x2 = x_tf + bn(merge_raw); writes fp32 + bf16
// ---------------------------------------------------------------------------
__global__ __launch_bounds__(256) void x2_kernel(
    const float* __restrict__ raw, const float* __restrict__ st,
    const float* __restrict__ xtf, float* __restrict__ x2f, short* __restrict__ x2bf)
{
    int t = blockIdx.x * 256 + threadIdx.x;     // ROWS*96
    int row = t / 96, c = (t % 96) * 4;
    size_t idx = (size_t)row * 384 + c;
    float4 v = *(const float4*)&raw[idx];
    float4 xr = *(const float4*)&xtf[idx];
    float4 sa = *(const float4*)&st[c * 2];
    float4 sb = *(const float4*)&st[c * 2 + 4];
    float o0 = xr.x + v.x * sa.x + sa.y;
    float o1 = xr.y + v.y * sa.z + sa.w;
    float o2 = xr.z + v.z * sb.x + sb.y;
    float o3 = xr.w + v.w * sb.z + sb.w;
    *(float4*)&x2f[idx] = make_float4(o0, o1, o2, o3);
    *(unsigned long long*)&x2bf[idx] = pack4bf(o0, o1, o2, o3);
}

// ---------------------------------------------------------------------------
// h = gelu(bn(fc1_raw)) -> bf16
// ---------------------------------------------------------------------------
__global__ __launch_bounds__(256) void h_kernel(
    const float* __restrict__ raw, const float* __restrict__ st, short* __restrict__ hbf)
{
    int t = blockIdx.x * 256 + threadIdx.x;     // ROWS*192
    int row = t / 192, c = (t % 192) * 4;
    size_t idx = (size_t)row * 768 + c;
    float4 v = *(const float4*)&raw[idx];
    float4 sa = *(const float4*)&st[c * 2];
    float4 sb = *(const float4*)&st[c * 2 + 4];
    float o0 = gelu_exact(v.x * sa.x + sa.y);
    float o1 = gelu_exact(v.y * sa.z + sa.w);
    float o2 = gelu_exact(v.z * sb.x + sb.y);
    float o3 = gelu_exact(v.w * sb.z + sb.w);
    *(unsigned long long*)&hbf[idx] = pack4bf(o0, o1, o2, o3);
}

// ---------------------------------------------------------------------------
// out[b][c][n] = x2f[row][c] + bn(fc2_raw[row][c])   (transposed store)
// ---------------------------------------------------------------------------
__global__ __launch_bounds__(256) void final_tr(
    const float* __restrict__ raw, const float* __restrict__ st,
    const float* __restrict__ x2f, float* __restrict__ out)
{
    __shared__ float ls[64][65];
    const int b = blockIdx.z, c0 = blockIdx.y * 64, n0 = blockIdx.x * 64;
    const int rl = threadIdx.x >> 6, ll = threadIdx.x & 63;
    const int c = c0 + ll;
    const float sc = st[c * 2], sh = st[c * 2 + 1];
    #pragma unroll
    for (int it = 0; it < 16; ++it) {
        int n = rl + it * 4;
        size_t idx = ((size_t)b * NPIX + n0 + n) * 384 + c;
        ls[n][ll] = x2f[idx] + raw[idx] * sc + sh;
    }
    __syncthreads();
    #pragma unroll
    for (int it = 0; it < 16; ++it) {
        int cr = rl + it * 4;
        out[((size_t)b * 384 + c0 + cr) * NPIX + n0 + ll] = ls[ll][cr];
    }
}

// ---------------------------------------------------------------------------
extern "C" void kernel_launch(void* const* d_in, const int* in_sizes, int n_in,
                              void* d_out, int out_size, void* d_ws, size_t ws_size,
                              hipStream_t stream)
{
    const float* x       = (const float*)d_in[0];
    const float* w_qkv   = (const float*)d_in[1];
    const float* g_qkv   = (const float*)d_in[2];
    const float* b_qkv   = (const float*)d_in[3];
    const float* w_merge = (const float*)d_in[4];
    const float* g_merge = (const float*)d_in[5];
    const float* b_merge = (const float*)d_in[6];
    const float* w_fc1   = (const float*)d_in[7];
    const float* g_fc1   = (const float*)d_in[8];
    const float* b_fc1   = (const float*)d_in[9];
    const float* w_fc2   = (const float*)d_in[10];
    const float* g_fc2   = (const float*)d_in[11];
    const float* b_fc2   = (const float*)d_in[12];
    float* out = (float*)d_out;

    char* ws = (char*)d_ws;
    short* wq_bf   = (short*)(ws + 0);            // 1,179,648 B
    short* wm_bf   = (short*)(ws + 1179648);      //   786,432
    short* wf1_bf  = (short*)(ws + 1966080);      //   589,824
    short* wf2_bf  = (short*)(ws + 2555904);      //   589,824
    short* x_bf    = (short*)(ws + 3145728);      // 6,291,456
    float* x_tf    = (float*)(ws + 9437184);      // 12,582,912
    float* qkv_raw = (float*)(ws + 22020096);     // 50,331,648 (dies after v_transpose)
    short* qk_bf   = (short*)(ws + 72351744);     // 8,388,608
    short* vt      = (short*)(ws + 80740352);     // 16,777,216
    short* attn_bf = (short*)(ws + 22020096);     // 16,777,216 (reuse qkv_raw[0:16.8M])
    float* fc1_raw = (float*)(ws + 38797312);     // 25,165,824 (reuse qkv_raw[16.8M:42M])
    float* fc2_raw = (float*)(ws + 22020096);     // 12,582,912 (reuse attn_bf slot, dead then)
    short* h_bf    = (short*)(ws + 80740352);     // 12,582,912 (reuse vt slot, dead then)
    float* merge_raw = (float*)(ws + 97517568);   // 12,582,912
    short* x2_bf   = (short*)(ws + 110100480);    // 6,291,456
    float* x2_f    = (float*)(ws + 116391936);    // 12,582,912
    float* sums    = (float*)(ws + 128974848);    // 3072 ch * 2 = 24,576 B
    float* stats   = (float*)(ws + 128999424);    // 24,576 B  (end ~129 MB)

    float* sums_qkv = sums;
    float* sums_mg  = sums + 1536 * 2;
    float* sums_f1  = sums + (1536 + 384) * 2;
    float* sums_f2  = sums + (1536 + 384 + 768) * 2;
    float* st_qkv = stats;
    float* st_mg  = stats + 1536 * 2;
    float* st_f1  = stats + (1536 + 384) * 2;
    float* st_f2  = stats + (1536 + 384 + 768) * 2;

    hipMemsetAsync(sums, 0, 3072 * 2 * sizeof(float), stream);

    cast_bf<<<288, 256, 0, stream>>>(w_qkv, wq_bf, 1536 * 384 / 8);
    cast_bf<<<192, 256, 0, stream>>>(w_merge, wm_bf, 384 * 1024 / 8);
    cast_bf<<<144, 256, 0, stream>>>(w_fc1, wf1_bf, 768 * 384 / 8);
    cast_bf<<<144, 256, 0, stream>>>(w_fc2, wf2_bf, 384 * 768 / 8);

    x_transpose<<<dim3(16, 6, 8), 256, 0, stream>>>(x, x_bf, x_tf);

    gemm_bf16<<<dim3(64, 12), 256, 0, stream>>>(x_bf, wq_bf, qkv_raw, sums_qkv, 1536, 384);
    bn_finalize<<<6, 256, 0, stream>>>(sums_qkv, g_qkv, b_qkv, st_qkv, 1536);
    qkv_post<<<4096, 256, 0, stream>>>(qkv_raw, st_qkv, qk_bf);
    v_transpose<<<dim3(16, 2, 64), 256, 0, stream>>>(qkv_raw, st_qkv, vt);

    attn_kernel<<<dim3(8, 8, 8), 256, 0, stream>>>(qk_bf, vt, attn_bf);

    gemm_bf16<<<dim3(64, 3), 256, 0, stream>>>(attn_bf, wm_bf, merge_raw, sums_mg, 384, 1024);
    bn_finalize<<<2, 256, 0, stream>>>(sums_mg, g_merge, b_merge, st_mg, 384);
    x2_kernel<<<3072, 256, 0, stream>>>(merge_raw, st_mg, x_tf, x2_f, x2_bf);

    gemm_bf16<<<dim3(64, 6), 256, 0, stream>>>(x2_bf, wf1_bf, fc1_raw, sums_f1, 768, 384);
    bn_finalize<<<3, 256, 0, stream>>>(sums_f1, g_fc1, b_fc1, st_f1, 768);
    h_kernel<<<6144, 256, 0, stream>>>(fc1_raw, st_f1, h_bf);

    gemm_bf16<<<dim3(64, 3), 256, 0, stream>>>(h_bf, wf2_bf, fc2_raw, sums_f2, 384, 768);
    bn_finalize<<<2, 256, 0, stream>>>(sums_f2, g_fc2, b_fc2, st_f2, 384);
    final_tr<<<dim3(16, 6, 8), 256, 0, stream>>>(fc2_raw, st_f2, x2_f, out);
}